// Round 16
// baseline (61.991 us; speedup 1.0000x reference)
//
#include <hip/hip_runtime.h>

#define TWO_LOG2E 2.8853901817779268f   // 2*log2(e)
#define LOG2E     1.4426950408889634f

typedef float f32x2 __attribute__((ext_vector_type(2)));
typedef int   i32x4 __attribute__((ext_vector_type(4)));

// quad_perm DPP cross-lane (VALU pipe)
template<int CTRL>
__device__ __forceinline__ float dpp_qperm(float x) {
    int r = __builtin_amdgcn_update_dpp(0, __float_as_int(x), CTRL, 0xF, 0xF, true);
    return __int_as_float(r);
}

__device__ __forceinline__ f32x2 splat2(float s) { f32x2 v; v.x = s; v.y = s; return v; }

// R12 quad layout + math, but each thread owns 4 CONSECUTIVE edges (block
// b = tid>>2): the 8 strided idx loads per group collapse to 2 int4 loads.
// Vmem wave-insts per 64-edge group: 20 -> 14. Theory: TA processes each vmem
// wave-inst at ~4 lane-addr/cyc regardless of coalescing (fits R12==R15 and
// the structure-invariant ~26us stall); fewer insts is the only lever.
// Stores are PLAIN (not nt): stride-4-in-wave quads must write-combine in L2
// (R15's nt partial-line stores amplified WRITE 50->60MB).
__global__ void edge_mlp(
    const float* __restrict__ m,     // [N_NODES, 4, 2]
    const int*   __restrict__ eidx,  // [2, E]
    const float* __restrict__ W1,    // [4, 4, 8]
    const float* __restrict__ b1,    // [4, 8]
    const float* __restrict__ W2,    // [4, 8, 1]
    const float* __restrict__ b2,    // [4, 1]
    float*       __restrict__ out,   // [E, 4]
    const int nE)
{
    __shared__ __align__(16) float sw1[4 * 36]; // [c][p][i][01]=W1[c][i][2p+?]*2log2e
    __shared__ __align__(16) float sbw[4 * 18]; // [c][p]={b1 pair, -2*2log2e*W2 pair}
    __shared__ float so0[4];                    // 2log2e*(b2[c] + sum_j W2[c][j])

    const int tidb = threadIdx.x;
    if (tidb < 128) {
        const int c = tidb >> 5, r = tidb & 31, i = r >> 3, j = r & 7;
        sw1[c * 36 + (j >> 1) * 8 + i * 2 + (j & 1)] =
            W1[c * 32 + i * 8 + j] * TWO_LOG2E;
    } else if (tidb < 192) {
        const int q = tidb - 128, c = q >> 4, r = q & 15, p = r >> 2, k = r & 3;
        const int j = 2 * p + (k & 1);
        sbw[c * 18 + p * 4 + k] =
            (k < 2) ? b1[c * 8 + j] * TWO_LOG2E
                    : W2[c * 8 + j] * (-2.0f * TWO_LOG2E);
    } else if (tidb < 196) {
        const int c = tidb - 192;
        float s = b2[c];
        #pragma unroll
        for (int j = 0; j < 8; ++j) s += W2[c * 8 + j];
        so0[c] = s * TWO_LOG2E;
    }
    __syncthreads();

    const int tid0 = blockIdx.x * blockDim.x + threadIdx.x;
    const int c = tid0 & 3;
    const int cc2 = c * 2;
    const float* w1c = sw1 + c * 36;
    const f32x2* bwc = (const f32x2*)(sbw + c * 18);
    const float o0 = so0[c];

    const int* eidx1 = eidx + nE;               // col list
    const int stride  = gridDim.x * blockDim.x;
    const int bstride = stride >> 2;            // 4-edge blocks per grid pass
    const int nBlk    = nE >> 2;                // complete 4-edge blocks

    for (int b = tid0 >> 2; b < nBlk; b += bstride) {
        // one int4 per list: idx for 4 consecutive edges (16B/lane, fully used)
        const i32x4 rows = __builtin_nontemporal_load((const i32x4*)eidx  + b);
        const i32x4 cols = __builtin_nontemporal_load((const i32x4*)eidx1 + b);

        f32x2 mc[4], mr[4];
        #pragma unroll
        for (int k = 0; k < 4; ++k) {
            mc[k] = *(const f32x2*)(m + (unsigned)cols[k] * 8u + cc2);
            mr[k] = *(const f32x2*)(m + (unsigned)rows[k] * 8u + cc2);
        }
        #pragma unroll
        for (int k = 0; k < 4; ++k) {
            float o = o0;                          // scaled domain (x 2log2e)
            #pragma unroll
            for (int p = 0; p < 4; ++p) {          // j-pair p: packed layer-1
                const f32x2* wp = (const f32x2*)(w1c + p * 8);
                f32x2 h = bwc[p * 2];              // bb01
                h = __builtin_elementwise_fma(splat2(mc[k].x), wp[0], h);
                h = __builtin_elementwise_fma(splat2(mc[k].y), wp[1], h);
                h = __builtin_elementwise_fma(splat2(mr[k].x), wp[2], h);
                h = __builtin_elementwise_fma(splat2(mr[k].y), wp[3], h);
                const float a0 = __builtin_amdgcn_exp2f(h.x) + 1.0f; // 1+e^{2x}
                const float a1 = __builtin_amdgcn_exp2f(h.y) + 1.0f;
                const float inv = __builtin_amdgcn_rcpf(a0 * a1);
                const f32x2 w2n01 = bwc[p * 2 + 1];
                o = fmaf(w2n01.x, inv * a1, o);    // tanh0 * w2_0 (folded)
                o = fmaf(w2n01.y, inv * a0, o);    // tanh1 * w2_1
            }
            const float e2 = __builtin_amdgcn_exp2f(o);
            const float r2 = __builtin_amdgcn_rcpf(e2 + 1.0f);
            // eo = e^{tanh(o_true)} = 2^{LOG2E - TWO_LOG2E*r2}
            const float eo = __builtin_amdgcn_exp2f(fmaf(-TWO_LOG2E, r2, LOG2E));
            // quad = 4 classes of edge 4b+k (uniform k): softmax via DPP
            float s = eo + dpp_qperm<0xB1>(eo);
            s = s + dpp_qperm<0x4E>(s);
            out[b * 16 + k * 4 + c] = eo * __builtin_amdgcn_rcpf(s); // plain store
        }
    }

    // tail: leftover edges (nE % 4; empty for the bench shape)
    const int total = nE * 4;
    for (int t = nBlk * 16 + tid0; t < total; t += stride) {
        const int e  = t >> 2;
        const int cc = t & 3;
        const int r0 = eidx[e];
        const int c0 = eidx1[e];
        const float* w1t = sw1 + cc * 36;
        const f32x2* bwt = (const f32x2*)(sbw + cc * 18);
        const f32x2 mcv = *(const f32x2*)(m + (unsigned)c0 * 8u + cc * 2);
        const f32x2 mrv = *(const f32x2*)(m + (unsigned)r0 * 8u + cc * 2);
        float o = so0[cc];
        #pragma unroll
        for (int p = 0; p < 4; ++p) {
            const f32x2* wp = (const f32x2*)(w1t + p * 8);
            f32x2 h = bwt[p * 2];
            h = __builtin_elementwise_fma(splat2(mcv.x), wp[0], h);
            h = __builtin_elementwise_fma(splat2(mcv.y), wp[1], h);
            h = __builtin_elementwise_fma(splat2(mrv.x), wp[2], h);
            h = __builtin_elementwise_fma(splat2(mrv.y), wp[3], h);
            const float a0 = __builtin_amdgcn_exp2f(h.x) + 1.0f;
            const float a1 = __builtin_amdgcn_exp2f(h.y) + 1.0f;
            const float inv = __builtin_amdgcn_rcpf(a0 * a1);
            const f32x2 w2n01 = bwt[p * 2 + 1];
            o = fmaf(w2n01.x, inv * a1, o);
            o = fmaf(w2n01.y, inv * a0, o);
        }
        const float e2 = __builtin_amdgcn_exp2f(o);
        const float r2 = __builtin_amdgcn_rcpf(e2 + 1.0f);
        const float eo = __builtin_amdgcn_exp2f(fmaf(-TWO_LOG2E, r2, LOG2E));
        // cannot rely on quad structure in tail: recompute softmax serially
        float den = 0.0f;
        #pragma unroll
        for (int oc = 0; oc < 4; ++oc) {
            const float* w1o = sw1 + oc * 36;
            const f32x2* bwo = (const f32x2*)(sbw + oc * 18);
            const f32x2 mco = *(const f32x2*)(m + (unsigned)c0 * 8u + oc * 2);
            const f32x2 mro = *(const f32x2*)(m + (unsigned)r0 * 8u + oc * 2);
            float oo = so0[oc];
            #pragma unroll
            for (int p = 0; p < 4; ++p) {
                const f32x2* wp = (const f32x2*)(w1o + p * 8);
                f32x2 h = bwo[p * 2];
                h = __builtin_elementwise_fma(splat2(mco.x), wp[0], h);
                h = __builtin_elementwise_fma(splat2(mco.y), wp[1], h);
                h = __builtin_elementwise_fma(splat2(mro.x), wp[2], h);
                h = __builtin_elementwise_fma(splat2(mro.y), wp[3], h);
                const float a0 = __builtin_amdgcn_exp2f(h.x) + 1.0f;
                const float a1 = __builtin_amdgcn_exp2f(h.y) + 1.0f;
                const float inv = __builtin_amdgcn_rcpf(a0 * a1);
                const f32x2 w2n01 = bwo[p * 2 + 1];
                oo = fmaf(w2n01.x, inv * a1, oo);
                oo = fmaf(w2n01.y, inv * a0, oo);
            }
            const float e2o = __builtin_amdgcn_exp2f(oo);
            const float r2o = __builtin_amdgcn_rcpf(e2o + 1.0f);
            den += __builtin_amdgcn_exp2f(fmaf(-TWO_LOG2E, r2o, LOG2E));
        }
        out[t] = eo * __builtin_amdgcn_rcpf(den);
    }
}

extern "C" void kernel_launch(void* const* d_in, const int* in_sizes, int n_in,
                              void* d_out, int out_size, void* d_ws, size_t ws_size,
                              hipStream_t stream) {
    const float* m  = (const float*)d_in[0];
    const int* eidx = (const int*)d_in[1];
    const float* W1 = (const float*)d_in[2];
    const float* b1 = (const float*)d_in[3];
    const float* W2 = (const float*)d_in[4];
    const float* b2 = (const float*)d_in[5];
    float* out = (float*)d_out;
    const int nE = in_sizes[1] / 2;

    const int threads = 256;
    const int blocks  = 2048;
    hipLaunchKernelGGL(edge_mlp, dim3(blocks), dim3(threads), 0, stream,
                       m, eidx, W1, b1, W2, b2, out, nE);
}

// Round 18
// 56.991 us; speedup vs baseline: 1.0877x; 1.0877x over previous
//
#include <hip/hip_runtime.h>

#define TWO_LOG2E 2.8853901817779268f   // 2*log2(e)
#define LOG2E     1.4426950408889634f

typedef float f32x2 __attribute__((ext_vector_type(2)));
typedef float f32x4 __attribute__((ext_vector_type(4)));

// quad_perm DPP (VALU pipe). 0xB1 = [1,0,3,2] lane^1 swap, 0x4E = [2,3,0,1].
template<int CTRL>
__device__ __forceinline__ float dpp_qperm(float x) {
    int r = __builtin_amdgcn_update_dpp(0, __float_as_int(x), CTRL, 0xF, 0xF, true);
    return __int_as_float(r);
}
__device__ __forceinline__ f32x4 qswap4(f32x4 v) {   // each lane gets lane^1's vec
    f32x4 r;
    r.x = dpp_qperm<0xB1>(v.x); r.y = dpp_qperm<0xB1>(v.y);
    r.z = dpp_qperm<0xB1>(v.z); r.w = dpp_qperm<0xB1>(v.w);
    return r;
}
__device__ __forceinline__ f32x2 splat2(float s) { f32x2 v; v.x = s; v.y = s; return v; }

// QUAD-COOPERATIVE GATHER: quad = one edge, lane c = class. Per slot ONE b128
// wave-inst loads both 32B node rows (lane0:col-lo, lane1:row-lo, lane2:col-hi,
// lane3:row-hi) -> gather lane-requests 8->4 per edge. R17 failed on a row/col
// list swap (even lanes must read the COL list = eidx+nE since their pieces
// feed mc); fixed here, distribution logic verified per-lane.
__global__ void edge_mlp(
    const float* __restrict__ m,     // [N_NODES, 4, 2]
    const int*   __restrict__ eidx,  // [2, E]  (row=eidx[0], col=eidx[1])
    const float* __restrict__ W1,    // [4, 4, 8]
    const float* __restrict__ b1,    // [4, 8]
    const float* __restrict__ W2,    // [4, 8, 1]
    const float* __restrict__ b2,    // [4, 1]
    float*       __restrict__ out,   // [E, 4]
    const int nE)
{
    __shared__ __align__(16) float sw1[4 * 36]; // [c][p][i][01]=W1[c][i][2p+?]*2log2e
    __shared__ __align__(16) float sbw[4 * 18]; // [c][p]={b1 pair, -2*2log2e*W2 pair}
    __shared__ float so0[4];                    // 2log2e*(b2[c] + sum_j W2[c][j])

    const int tidb = threadIdx.x;
    if (tidb < 128) {
        const int c = tidb >> 5, r = tidb & 31, i = r >> 3, j = r & 7;
        sw1[c * 36 + (j >> 1) * 8 + i * 2 + (j & 1)] =
            W1[c * 32 + i * 8 + j] * TWO_LOG2E;
    } else if (tidb < 192) {
        const int q = tidb - 128, c = q >> 4, r = q & 15, p = r >> 2, k = r & 3;
        const int j = 2 * p + (k & 1);
        sbw[c * 18 + p * 4 + k] =
            (k < 2) ? b1[c * 8 + j] * TWO_LOG2E
                    : W2[c * 8 + j] * (-2.0f * TWO_LOG2E);
    } else if (tidb < 196) {
        const int c = tidb - 192;
        float s = b2[c];
        #pragma unroll
        for (int j = 0; j < 8; ++j) s += W2[c * 8 + j];
        so0[c] = s * TWO_LOG2E;
    }
    __syncthreads();

    const int tid0 = blockIdx.x * blockDim.x + threadIdx.x;
    const int c    = tid0 & 3;                   // class = lane-in-quad
    const bool odd = (c & 1);                    // even lanes: col piece; odd: row
    const unsigned halfOfs = (unsigned)((c >> 1) & 1) * 4u;  // lo/hi 16B of row
    const float* w1c = sw1 + c * 36;
    const f32x2* bwc = (const f32x2*)(sbw + c * 18);
    const float o0 = so0[c];

    const int* rowlist = eidx;                   // edge_index[0]
    const int* collist = eidx + nE;              // edge_index[1]
    const int* mylist  = odd ? rowlist : collist; // FIXED: even->col, odd->row
    const int nQuads = (gridDim.x * blockDim.x) >> 2;

    constexpr int UN = 4;
    int e0 = tid0 >> 2;

    for (; e0 + (UN - 1) * nQuads < nE; e0 += UN * nQuads) {
        int idx[UN];
        #pragma unroll
        for (int k = 0; k < UN; ++k)             // 1 inst/slot (2x-redundant)
            idx[k] = __builtin_nontemporal_load(mylist + e0 + k * nQuads);
        f32x4 pc[UN];
        #pragma unroll
        for (int k = 0; k < UN; ++k)             // ONE b128 gather per slot
            pc[k] = *(const f32x4*)(m + (unsigned)idx[k] * 8u + halfOfs);

        #pragma unroll
        for (int k = 0; k < UN; ++k) {
            const f32x4 nb = qswap4(pc[k]);      // neighbor's piece
            f32x2 mc, mr;                        // this class's 4 features
            // even lane c: own=col half -> mc = pc.{x,y} at word 2c; mr = nb.{x,y}
            // odd  lane c: own=row half -> mc = nb.{z,w};  mr = pc.{z,w}
            mc.x = odd ? nb.z    : pc[k].x;  mc.y = odd ? nb.w    : pc[k].y;
            mr.x = odd ? pc[k].z : nb.x;     mr.y = odd ? pc[k].w : nb.y;

            float o = o0;                        // scaled domain (x 2log2e)
            #pragma unroll
            for (int p = 0; p < 4; ++p) {        // j-pair p: packed layer-1
                const f32x2* wp = (const f32x2*)(w1c + p * 8);
                f32x2 h = bwc[p * 2];            // bb01
                h = __builtin_elementwise_fma(splat2(mc.x), wp[0], h);
                h = __builtin_elementwise_fma(splat2(mc.y), wp[1], h);
                h = __builtin_elementwise_fma(splat2(mr.x), wp[2], h);
                h = __builtin_elementwise_fma(splat2(mr.y), wp[3], h);
                const float a0 = __builtin_amdgcn_exp2f(h.x) + 1.0f; // 1+e^{2x}
                const float a1 = __builtin_amdgcn_exp2f(h.y) + 1.0f;
                const float inv = __builtin_amdgcn_rcpf(a0 * a1);
                const f32x2 w2n01 = bwc[p * 2 + 1];
                o = fmaf(w2n01.x, inv * a1, o);  // tanh0 * w2_0 (folded)
                o = fmaf(w2n01.y, inv * a0, o);  // tanh1 * w2_1
            }
            const float e2 = __builtin_amdgcn_exp2f(o);
            const float r2 = __builtin_amdgcn_rcpf(e2 + 1.0f);
            const float eo = __builtin_amdgcn_exp2f(fmaf(-TWO_LOG2E, r2, LOG2E));
            float s = eo + dpp_qperm<0xB1>(eo);  // quad softmax denom
            s = s + dpp_qperm<0x4E>(s);
            // 64 lanes -> 256B contiguous: fully coalesced
            __builtin_nontemporal_store(eo * __builtin_amdgcn_rcpf(s),
                out + ((unsigned)(e0 + k * nQuads) << 2) + c);
        }
    }

    // tail: one slot at a time
    for (; e0 < nE; e0 += nQuads) {
        const int idx = __builtin_nontemporal_load(mylist + e0);
        const f32x4 piece = *(const f32x4*)(m + (unsigned)idx * 8u + halfOfs);
        const f32x4 nb = qswap4(piece);
        f32x2 mc, mr;
        mc.x = odd ? nb.z    : piece.x;  mc.y = odd ? nb.w    : piece.y;
        mr.x = odd ? piece.z : nb.x;     mr.y = odd ? piece.w : nb.y;
        float o = o0;
        #pragma unroll
        for (int p = 0; p < 4; ++p) {
            const f32x2* wp = (const f32x2*)(w1c + p * 8);
            f32x2 h = bwc[p * 2];
            h = __builtin_elementwise_fma(splat2(mc.x), wp[0], h);
            h = __builtin_elementwise_fma(splat2(mc.y), wp[1], h);
            h = __builtin_elementwise_fma(splat2(mr.x), wp[2], h);
            h = __builtin_elementwise_fma(splat2(mr.y), wp[3], h);
            const float a0 = __builtin_amdgcn_exp2f(h.x) + 1.0f;
            const float a1 = __builtin_amdgcn_exp2f(h.y) + 1.0f;
            const float inv = __builtin_amdgcn_rcpf(a0 * a1);
            const f32x2 w2n01 = bwc[p * 2 + 1];
            o = fmaf(w2n01.x, inv * a1, o);
            o = fmaf(w2n01.y, inv * a0, o);
        }
        const float e2 = __builtin_amdgcn_exp2f(o);
        const float r2 = __builtin_amdgcn_rcpf(e2 + 1.0f);
        const float eo = __builtin_amdgcn_exp2f(fmaf(-TWO_LOG2E, r2, LOG2E));
        float s = eo + dpp_qperm<0xB1>(eo);
        s = s + dpp_qperm<0x4E>(s);
        out[((unsigned)e0 << 2) + c] = eo * __builtin_amdgcn_rcpf(s);
    }
}

extern "C" void kernel_launch(void* const* d_in, const int* in_sizes, int n_in,
                              void* d_out, int out_size, void* d_ws, size_t ws_size,
                              hipStream_t stream) {
    const float* m  = (const float*)d_in[0];
    const int* eidx = (const int*)d_in[1];
    const float* W1 = (const float*)d_in[2];
    const float* b1 = (const float*)d_in[3];
    const float* W2 = (const float*)d_in[4];
    const float* b2 = (const float*)d_in[5];
    float* out = (float*)d_out;
    const int nE = in_sizes[1] / 2;

    const int threads = 256;
    const int blocks  = 2048;
    hipLaunchKernelGGL(edge_mlp, dim3(blocks), dim3(threads), 0, stream,
                       m, eidx, W1, b1, W2, b2, out, nE);
}

// Round 20
// 55.607 us; speedup vs baseline: 1.1148x; 1.0249x over previous
//
#include <hip/hip_runtime.h>

#define TWO_LOG2E 2.8853901817779268f   // 2*log2(e)
#define LOG2E     1.4426950408889634f

typedef float f32x2 __attribute__((ext_vector_type(2)));

// quad_perm DPP cross-lane (VALU pipe)
template<int CTRL>
__device__ __forceinline__ float dpp_qperm(float x) {
    int r = __builtin_amdgcn_update_dpp(0, __float_as_int(x), CTRL, 0xF, 0xF, true);
    return __int_as_float(r);
}

__device__ __forceinline__ f32x2 splat2(float s) { f32x2 v; v.x = s; v.y = s; return v; }

// One thread per (edge, class); lane's class c = tid & 3. Weights in LDS
// (R10 win), padded strides (R11: conflicts ~0), packed f32x2 layer-1 FMAs,
// single-exp2 softmax numerator. Best measured config of the session: 54.8us.
__global__ __launch_bounds__(256) void edge_mlp(
    const float* __restrict__ m,     // [N_NODES, 4, 2]
    const int*   __restrict__ eidx,  // [2, E]
    const float* __restrict__ W1,    // [4, 4, 8]
    const float* __restrict__ b1,    // [4, 8]
    const float* __restrict__ W2,    // [4, 8, 1]
    const float* __restrict__ b2,    // [4, 1]
    float*       __restrict__ out,   // [E, 4]
    const int nE)
{
    // sw1[c][p][i] = f32x2 {W1[c][i][2p], W1[c][i][2p+1]} * 2log2e
    __shared__ __align__(16) float sw1[4 * 36];
    // sbw[c][p] = {bb01 (f32x2), w2n01 (f32x2)}; class stride 18 floats.
    __shared__ __align__(16) float sbw[4 * 18];
    __shared__ float so0[4];         // 2log2e*(b2[c] + sum_j W2[c][j])

    const int tidb = threadIdx.x;
    if (tidb < 128) {                // (c,i,j) -> paired layout
        const int c = tidb >> 5, r = tidb & 31, i = r >> 3, j = r & 7;
        sw1[c * 36 + (j >> 1) * 8 + i * 2 + (j & 1)] =
            W1[c * 32 + i * 8 + j] * TWO_LOG2E;
    } else if (tidb < 192) {
        const int q = tidb - 128, c = q >> 4, r = q & 15, p = r >> 2, k = r & 3;
        const int j = 2 * p + (k & 1);
        sbw[c * 18 + p * 4 + k] =
            (k < 2) ? b1[c * 8 + j] * TWO_LOG2E
                    : W2[c * 8 + j] * (-2.0f * TWO_LOG2E);
    } else if (tidb < 196) {
        const int c = tidb - 192;
        float s = b2[c];
        #pragma unroll
        for (int j = 0; j < 8; ++j) s += W2[c * 8 + j];
        so0[c] = s * TWO_LOG2E;
    }
    __syncthreads();

    const int tid0 = blockIdx.x * blockDim.x + threadIdx.x;
    const int c = tid0 & 3;
    const int cc2 = c * 2;
    const float* w1c = sw1 + c * 36;
    const f32x2* bwc = (const f32x2*)(sbw + c * 18);
    const float o0 = so0[c];

    const int* eidx1 = eidx + nE;
    const int total  = nE * 4;
    const int stride = gridDim.x * blockDim.x;   // multiple of 4 -> c constant

    constexpr int UN = 4;
    int t = tid0;

    for (; t + (UN - 1) * stride < total; t += UN * stride) {
        int row[UN], col[UN];
        #pragma unroll
        for (int k = 0; k < UN; ++k) {
            const int e = (t + k * stride) >> 2;
            row[k] = __builtin_nontemporal_load(eidx  + e);
            col[k] = __builtin_nontemporal_load(eidx1 + e);
        }
        f32x2 mc[UN], mr[UN];
        #pragma unroll
        for (int k = 0; k < UN; ++k) {
            mc[k] = *(const f32x2*)(m + (unsigned)col[k] * 8u + cc2);
            mr[k] = *(const f32x2*)(m + (unsigned)row[k] * 8u + cc2);
        }
        #pragma unroll
        for (int k = 0; k < UN; ++k) {
            float o = o0;                          // scaled domain (x 2log2e)
            #pragma unroll
            for (int p = 0; p < 4; ++p) {          // j-pair p: packed layer-1
                const f32x2* wp = (const f32x2*)(w1c + p * 8);
                f32x2 h = bwc[p * 2];              // bb01
                h = __builtin_elementwise_fma(splat2(mc[k].x), wp[0], h);
                h = __builtin_elementwise_fma(splat2(mc[k].y), wp[1], h);
                h = __builtin_elementwise_fma(splat2(mr[k].x), wp[2], h);
                h = __builtin_elementwise_fma(splat2(mr[k].y), wp[3], h);
                const float a0 = __builtin_amdgcn_exp2f(h.x) + 1.0f; // 1+e^{2x}
                const float a1 = __builtin_amdgcn_exp2f(h.y) + 1.0f;
                const float inv = __builtin_amdgcn_rcpf(a0 * a1);
                const f32x2 w2n01 = bwc[p * 2 + 1];
                o = fmaf(w2n01.x, inv * a1, o);    // tanh0 * w2_0 (folded)
                o = fmaf(w2n01.y, inv * a0, o);    // tanh1 * w2_1
            }
            const float e2 = __builtin_amdgcn_exp2f(o);
            const float r2 = __builtin_amdgcn_rcpf(e2 + 1.0f);
            // eo = e^{tanh(o_true)} = 2^{LOG2E - TWO_LOG2E*r2}
            const float eo = __builtin_amdgcn_exp2f(fmaf(-TWO_LOG2E, r2, LOG2E));
            float s = eo + dpp_qperm<0xB1>(eo);    // quad softmax denom
            s = s + dpp_qperm<0x4E>(s);
            __builtin_nontemporal_store(eo * __builtin_amdgcn_rcpf(s),
                                        out + (t + k * stride));
        }
    }

    // tail
    for (; t < total; t += stride) {
        const int e  = t >> 2;
        const int r0 = eidx[e];
        const int c0 = eidx1[e];
        const f32x2 mcv = *(const f32x2*)(m + (unsigned)c0 * 8u + cc2);
        const f32x2 mrv = *(const f32x2*)(m + (unsigned)r0 * 8u + cc2);
        float o = o0;
        #pragma unroll
        for (int p = 0; p < 4; ++p) {
            const f32x2* wp = (const f32x2*)(w1c + p * 8);
            f32x2 h = bwc[p * 2];
            h = __builtin_elementwise_fma(splat2(mcv.x), wp[0], h);
            h = __builtin_elementwise_fma(splat2(mcv.y), wp[1], h);
            h = __builtin_elementwise_fma(splat2(mrv.x), wp[2], h);
            h = __builtin_elementwise_fma(splat2(mrv.y), wp[3], h);
            const float a0 = __builtin_amdgcn_exp2f(h.x) + 1.0f;
            const float a1 = __builtin_amdgcn_exp2f(h.y) + 1.0f;
            const float inv = __builtin_amdgcn_rcpf(a0 * a1);
            const f32x2 w2n01 = bwc[p * 2 + 1];
            o = fmaf(w2n01.x, inv * a1, o);
            o = fmaf(w2n01.y, inv * a0, o);
        }
        const float e2 = __builtin_amdgcn_exp2f(o);
        const float r2 = __builtin_amdgcn_rcpf(e2 + 1.0f);
        const float eo = __builtin_amdgcn_exp2f(fmaf(-TWO_LOG2E, r2, LOG2E));
        float s = eo + dpp_qperm<0xB1>(eo);
        s = s + dpp_qperm<0x4E>(s);
        out[t] = eo * __builtin_amdgcn_rcpf(s);
    }
}

extern "C" void kernel_launch(void* const* d_in, const int* in_sizes, int n_in,
                              void* d_out, int out_size, void* d_ws, size_t ws_size,
                              hipStream_t stream) {
    const float* m  = (const float*)d_in[0];
    const int* eidx = (const int*)d_in[1];
    const float* W1 = (const float*)d_in[2];
    const float* b1 = (const float*)d_in[3];
    const float* W2 = (const float*)d_in[4];
    const float* b2 = (const float*)d_in[5];
    float* out = (float*)d_out;
    const int nE = in_sizes[1] / 2;

    const int threads = 256;
    const int blocks  = 2048;
    hipLaunchKernelGGL(edge_mlp, dim3(blocks), dim3(threads), 0, stream,
                       m, eidx, W1, b1, W2, b2, out, nE);
}